// Round 4
// baseline (827.799 us; speedup 1.0000x reference)
//
#include <hip/hip_runtime.h>
#include <hip/hip_bf16.h>
#include <stdint.h>
#include <stddef.h>

// Problem constants
#define BB 4
#define LL 2048
#define KNB 30
#define IND 128
#define OUTD 400
#define NGEMM 800           // 2*OUTD: [T | U] combined GEMM width
#define NQ (BB*LL)          // 8192 queries / rows
#define OUT_EIDX_OFF 98304000  // 4*2048*30*400

typedef short short8 __attribute__((ext_vector_type(8)));
typedef float f32x4 __attribute__((ext_vector_type(4)));

__device__ __forceinline__ unsigned short f2b(float f) {
    unsigned int u = __float_as_uint(f);
    unsigned int r = (u + 0x7FFFu + ((u >> 16) & 1u)) >> 16;  // RNE
    return (unsigned short)r;
}
__device__ __forceinline__ float b2f(unsigned short u) {
    return __uint_as_float(((unsigned int)u) << 16);
}

// ---------------------------------------------------------------------------
// K1: convert V -> bf16 (Vb), build transposed+concatenated W -> bf16 (Wt),
//     extract Xca planes (x,y,z) to compact fp32 buffer (coalesced source
//     for knn staging -- reading X directly in knn was a measured -26us
//     regression: 48B-stride loads amplified 2048x across blocks).
// ---------------------------------------------------------------------------
__global__ __launch_bounds__(256) void convert_kernel(
    const float* __restrict__ V, const float* __restrict__ W,
    const float* __restrict__ X,
    unsigned short* __restrict__ Vb, unsigned short* __restrict__ Wt,
    float* __restrict__ Xpl) {
    int bid = blockIdx.x;
    int t = threadIdx.x;
    if (bid < 1024) {
        // V: 1,048,576 floats, 4 per thread
        int g = bid * 256 + t;
        float4 v = ((const float4*)V)[g];
        ushort4 o;
        o.x = f2b(v.x); o.y = f2b(v.y); o.z = f2b(v.z); o.w = f2b(v.w);
        ((ushort4*)Vb)[g] = o;
    } else if (bid < 1424) {
        // Wt[n][c]: n<400 -> W[c,n]; n>=400 -> W[128+c, n-400]. 102,400 elems.
        int g = (bid - 1024) * 256 + t;
        int n = g >> 7, c = g & 127;
        float f = (n < OUTD) ? W[c * OUTD + n] : W[(IND + c) * OUTD + (n - OUTD)];
        Wt[g] = f2b(f);
    } else {
        // Xca planes: 3 * 8192 elems.  X[(m)*12 + 3 + c]
        int g = (bid - 1424) * 256 + t;   // [0, 24576)
        int c = g >> 13, m = g & 8191;
        Xpl[c * NQ + m] = X[(size_t)m * 12 + 3 + c];
    }
}

// ---------------------------------------------------------------------------
// K2 (fused): KNN + GEMM in ONE dispatch.  They are independent (both depend
// only on convert) and live on different pipes: knn is VALU-issue-bound,
// gemm is memory+MFMA-bound -- co-resident waves overlap (time ~= max, not
// sum, per the MFMA/VALU co-schedule property).  knn blocks are interleaved
// 1-in-4 with gemm blocks so both kinds fill the machine from t=0.
//
// KNN part: one WAVE per query (4 waves/block share the coord tile).
// Exact reference arithmetic, stable tie-break by index via u64 key
// (f32bits(D_adjust)<<32 | j).  Extraction poisons the HIGH WORD of the
// extracted slot (real keys have finite-float high words, so 0xFFFFFFFF
// never wins).  All per-lane arrays use compile-time indices -> registers.
//
// GEMM part: TU = Vb(8192x128) @ Wt^T -> bf16 TU(8192x800).  One wave per
// 16x16 tile, K=128 via 4x mfma_f32_16x16x32_bf16.
// ---------------------------------------------------------------------------
__global__ __launch_bounds__(256) void mid_kernel(
    const float* __restrict__ Xpl, const float* __restrict__ mask,
    int* __restrict__ idx_out, float* __restrict__ eidx_out,
    const unsigned short* __restrict__ Vb, const unsigned short* __restrict__ Wt,
    unsigned short* __restrict__ TU) {
    __shared__ float4 sc[LL];   // (x,y,z,mask) interleaved; knn blocks only

    int g = blockIdx.x;
    int t = threadIdx.x;
    int wid = t >> 6, lane = t & 63;
    bool is_knn = (g < 8192) && ((g & 3) == 0);

    if (is_knn) {
        int kb = g >> 2;                 // knn block id [0, 2048)
        int q = kb * 4 + wid;            // 4 queries per block, same batch b
        int b = q >> 11, l = q & 2047;
        int base = b * LL;

        for (int i = t; i < LL; i += 256) {
            float4 c;
            c.x = Xpl[base + i];
            c.y = Xpl[NQ + base + i];
            c.z = Xpl[2 * NQ + base + i];
            c.w = mask[base + i];
            sc[i] = c;
        }
        __syncthreads();

        float4 qc = sc[l];
        float qx = qc.x, qy = qc.y, qz = qc.z, qm = qc.w;

        // Pass 1: distances + row max (for the mask-adjust term)
        float d[32], m2[32];
        float lmax = -1.0f;
        #pragma unroll
        for (int s = 0; s < 32; s++) {
            int j = lane + 64 * s;
            float4 c = sc[j];
            float dx = __fsub_rn(qx, c.x);
            float dy = __fsub_rn(qy, c.y);
            float dz = __fsub_rn(qz, c.z);
            float d2 = __fadd_rn(__fadd_rn(__fadd_rn(__fmul_rn(dx, dx), __fmul_rn(dy, dy)),
                                           __fmul_rn(dz, dz)), 1e-6f);
            float mm = __fmul_rn(qm, c.w);
            float dd = __fmul_rn(mm, __fsqrt_rn(d2));
            d[s] = dd; m2[s] = mm;
            lmax = fmaxf(lmax, dd);
        }
        #pragma unroll
        for (int off = 1; off < 64; off <<= 1)
            lmax = fmaxf(lmax, __shfl_xor(lmax, off));
        float Dmax = lmax;

        // Pass 2: u64 keys (value<<32 | index) -- ascending order == reference
        unsigned long long k64[32];
        #pragma unroll
        for (int s = 0; s < 32; s++) {
            float dadj = __fadd_rn(d[s], __fmul_rn(__fsub_rn(1.0f, m2[s]), Dmax));
            k64[s] = (((unsigned long long)__float_as_uint(dadj)) << 32)
                   | (unsigned int)(lane + 64 * s);
        }

        // 30 extraction rounds: 4-chain ILP min scan + wave butterfly min,
        // then the winning lane poisons its extracted slot's high word.
        unsigned int myj = 0u;
        for (int k = 0; k < KNB; k++) {
            unsigned long long c0 = k64[0], c1 = k64[1], c2 = k64[2], c3 = k64[3];
            #pragma unroll
            for (int s = 4; s < 32; s += 4) {
                c0 = (k64[s]     < c0) ? k64[s]     : c0;
                c1 = (k64[s + 1] < c1) ? k64[s + 1] : c1;
                c2 = (k64[s + 2] < c2) ? k64[s + 2] : c2;
                c3 = (k64[s + 3] < c3) ? k64[s + 3] : c3;
            }
            c0 = (c1 < c0) ? c1 : c0;
            c2 = (c3 < c2) ? c3 : c2;
            unsigned long long lm = (c2 < c0) ? c2 : c0;
            #pragma unroll
            for (int off = 1; off < 64; off <<= 1) {
                unsigned long long o = __shfl_xor(lm, off);
                lm = (o < lm) ? o : lm;
            }
            unsigned int j = (unsigned int)lm;
            if ((j & 63u) == (unsigned int)lane) {
                int slot = (int)(j >> 6);
                #pragma unroll
                for (int s = 0; s < 32; s++)
                    if (s == slot) k64[s] |= 0xFFFFFFFF00000000ull;
            }
            if (lane == k) myj = j;
        }
        size_t qb = (size_t)q * KNB;
        if (lane < KNB) {
            idx_out[qb + lane] = (int)myj;
            eidx_out[qb + lane] = (float)myj;
        }
    } else {
        // gemm block id: count of non-knn blocks below g
        int gid = (g < 8192) ? (g - (g >> 2) - 1) : (g - 2048);   // [0, 6400)
        int tile = gid * 4 + wid;       // 25600 tiles
        int tm = tile / 50, tn = tile % 50;
        int r16 = lane & 15, quad = lane >> 4;

        const unsigned short* Abase = Vb + (size_t)(tm * 16 + r16) * IND + quad * 8;
        const unsigned short* Bbase = Wt + (size_t)(tn * 16 + r16) * IND + quad * 8;

        f32x4 acc = {0.f, 0.f, 0.f, 0.f};
        #pragma unroll
        for (int kk = 0; kk < IND; kk += 32) {
            short8 a = *(const short8*)(Abase + kk);
            short8 b = *(const short8*)(Bbase + kk);
            acc = __builtin_amdgcn_mfma_f32_16x16x32_bf16(a, b, acc, 0, 0, 0);
        }
        int col = lane & 15;
        #pragma unroll
        for (int r = 0; r < 4; r++) {
            int m = tm * 16 + quad * 4 + r;
            TU[(size_t)m * NGEMM + tn * 16 + col] = f2b(acc[r]);
        }
    }
}

// ---------------------------------------------------------------------------
// K4: epilogue.  TWO waves per (b,l): wave-half h covers k in [15h, 15h+15).
// XCD-aware block swizzle: 4096 blocks, blocks with bid%8==x land on XCD x;
// swizzle gives each XCD 1024 consecutive queries = ONE batch's panel
// (T+U gather footprint ~3.2MB < 4MB per-XCD L2) -> gathers become L2 hits
// instead of thrashing all 4 batches (13MB) through every XCD's L2.
// Row loads: one short8 (16B) per lane, 50 active lanes cover the 400-col
// half-row in a single load (replaces the 64+36 two-load split).  5 rows'
// gathers in flight per group (MLP=5).  idx row preloaded once, distributed
// via __shfl.  Output is write-once streaming -> nontemporal stores keep L2
// free for the reused TU panels.
// ---------------------------------------------------------------------------
__global__ __launch_bounds__(256) void epi_kernel(
    const unsigned short* __restrict__ TU, const int* __restrict__ idx,
    const float* __restrict__ bias, float* __restrict__ out) {
    int bid = blockIdx.x;
    int swz = (bid & 7) * 512 + (bid >> 3);   // bijective: 4096 % 8 == 0
    int t = threadIdx.x;
    int wid = t >> 6, lane = t & 63;
    int q = swz * 2 + (wid >> 1);   // 2 queries per block
    int half = wid & 1;             // which 15 of the 30 neighbors
    int b = q >> 11;

    const int* mi = idx + (size_t)q * KNB;
    int jv = (lane < KNB) ? mi[lane] : 0;  // one coalesced preload of all idx
    int i0 = __shfl(jv, 0);
    size_t rowbase = (size_t)(b * LL);
    const unsigned short* rowT = TU + (rowbase + i0) * NGEMM;

    bool act = lane < 50;
    int c0 = lane * 8;              // this lane's 8 columns
    float tb[8];
    if (act) {
        short8 u = *(const short8*)(rowT + c0);
        float4 b0 = *(const float4*)(bias + c0);
        float4 b1 = *(const float4*)(bias + c0 + 4);
        tb[0] = b2f((unsigned short)u[0]) + b0.x;
        tb[1] = b2f((unsigned short)u[1]) + b0.y;
        tb[2] = b2f((unsigned short)u[2]) + b0.z;
        tb[3] = b2f((unsigned short)u[3]) + b0.w;
        tb[4] = b2f((unsigned short)u[4]) + b1.x;
        tb[5] = b2f((unsigned short)u[5]) + b1.y;
        tb[6] = b2f((unsigned short)u[6]) + b1.z;
        tb[7] = b2f((unsigned short)u[7]) + b1.w;
    }

    size_t outbase = (size_t)q * KNB * OUTD;
    int kb0 = half * 15;
    for (int gi = 0; gi < 3; gi++) {
        int k0 = kb0 + gi * 5;
        int jj[5];
        #pragma unroll
        for (int e = 0; e < 5; e++) jj[e] = __shfl(jv, k0 + e);
        if (act) {
            short8 uu[5];
            #pragma unroll
            for (int e = 0; e < 5; e++)
                uu[e] = *(const short8*)(TU + (rowbase + jj[e]) * NGEMM + OUTD + c0);
            #pragma unroll
            for (int e = 0; e < 5; e++) {
                float* orow = out + outbase + (size_t)(k0 + e) * OUTD + c0;
                f32x4 o1, o2;
                o1.x = tb[0] + b2f((unsigned short)uu[e][0]);
                o1.y = tb[1] + b2f((unsigned short)uu[e][1]);
                o1.z = tb[2] + b2f((unsigned short)uu[e][2]);
                o1.w = tb[3] + b2f((unsigned short)uu[e][3]);
                o2.x = tb[4] + b2f((unsigned short)uu[e][4]);
                o2.y = tb[5] + b2f((unsigned short)uu[e][5]);
                o2.z = tb[6] + b2f((unsigned short)uu[e][6]);
                o2.w = tb[7] + b2f((unsigned short)uu[e][7]);
                __builtin_nontemporal_store(o1, (f32x4*)orow);
                __builtin_nontemporal_store(o2, (f32x4*)(orow + 4));
            }
        }
    }
}

extern "C" void kernel_launch(void* const* d_in, const int* in_sizes, int n_in,
                              void* d_out, int out_size, void* d_ws, size_t ws_size,
                              hipStream_t stream) {
    const float* X    = (const float*)d_in[0];
    const float* mask = (const float*)d_in[1];
    const float* V    = (const float*)d_in[2];
    const float* W    = (const float*)d_in[3];
    const float* bias = (const float*)d_in[4];
    float* out = (float*)d_out;

    char* ws = (char*)d_ws;
    unsigned short* Vb  = (unsigned short*)(ws);                 // 2,097,152 B
    unsigned short* Wt  = (unsigned short*)(ws + 2097152);       //   204,800 B
    float*          Xpl = (float*)(ws + 2301952);                //    98,304 B
    int*            idx = (int*)(ws + 2400256);                  //   983,040 B
    unsigned short* TU  = (unsigned short*)(ws + 3383296);       // 13,107,200 B
    // total ws use: ~15.7 MB

    convert_kernel<<<1520, 256, 0, stream>>>(V, W, X, Vb, Wt, Xpl);
    mid_kernel<<<8448, 256, 0, stream>>>(Xpl, mask, idx, out + OUT_EIDX_OFF,
                                         Vb, Wt, TU);
    epi_kernel<<<NQ / 2, 256, 0, stream>>>(TU, idx, bias, out);
}